// Round 16
// baseline (229.012 us; speedup 1.0000x reference)
//
#include <hip/hip_runtime.h>
#include <hip/hip_bf16.h>

#define DI __device__ __forceinline__

typedef __attribute__((ext_vector_type(8))) short bf16x8;
typedef __attribute__((ext_vector_type(4))) float f32x4;
typedef __attribute__((ext_vector_type(4))) short s16x4;

constexpr int S  = 1024;
constexpr int NH = 71;
constexpr int HD = 64;
constexpr int H  = NH * HD;        // 4544
constexpr int F  = (NH + 2) * HD;  // 4672
constexpr float K2 = 0.125f * 1.44269504f;  // SCALE * log2(e)

DI short f2bf(float f) {
  union { float f; unsigned u; } v; v.f = f;
  unsigned r = v.u + 0x7fffu + ((v.u >> 16) & 1u);
  return (short)(r >> 16);
}
DI unsigned cvt_pk_bf16(float lo, float hi) {
  unsigned r;
  asm("v_cvt_pk_bf16_f32 %0, %1, %2" : "=v"(r) : "v"(lo), "v"(hi));
  return r;
}
// reduce over lanes {lr, lr+16, lr+32, lr+48}: xor16 via ds_swizzle, xor32 via shfl
DI float redmax_g(float x) {
  float y = fmaxf(x, __int_as_float(__builtin_amdgcn_ds_swizzle(__float_as_int(x), 0x401F)));
  return fmaxf(y, __shfl_xor(y, 32));
}
DI float redsum_g(float x) {
  float y = x + __int_as_float(__builtin_amdgcn_ds_swizzle(__float_as_int(x), 0x401F));
  return y + __shfl_xor(y, 32);
}

DI void gload_lds16(const void* g, void* l) {
  __builtin_amdgcn_global_load_lds(
      (const __attribute__((address_space(1))) unsigned int*)g,
      (__attribute__((address_space(3))) unsigned int*)l, 16, 0, 0);
}

// swizzled LDS tile read: [64 rows][8 slots of 16B], slot XOR row&7
DI bf16x8 ldswz(const char* base, int row, int slot) {
  return *(const bf16x8*)(base + row * 128 + ((slot ^ (row & 7)) << 4));
}

// ---------------- cast x fp32 -> bf16 ----------------
__global__ void cast_x_kernel(const float* __restrict__ x, short* __restrict__ xb, int n4) {
  int i = blockIdx.x * blockDim.x + threadIdx.x;
  if (i >= n4) return;
  f32x4 v = ((const f32x4*)x)[i];
  s16x4 o = { f2bf(v.x), f2bf(v.y), f2bf(v.z), f2bf(v.w) };
  ((s16x4*)xb)[i] = o;
}

// ---------------- merged transpose+cast for BOTH weights (4x4 register transpose) ----
// W[K][N] f32 -> Wt[N][H] bf16 (K = H for both). Job 1: wqkv (N=F), job 2: wd (N=H).
// Thread owns a 4k x 4n f32 block: 4 independent f32x4 loads (register transpose
// DATA-FORCES all 4 in flight before the first LDS write -> MLP fixed), then
// 4x ds_write_b64 into rotated 16B slots (bank audit: 2-way worst = free).
// LDS row n: k-pos byte p=kq*8; slot s=p>>4 stored at ((s + (n>>2)) & 7)*16 + (p&15).
__global__ __launch_bounds__(256) void transpose2_kernel(
    const float* __restrict__ W1, short* __restrict__ Wt1,
    const float* __restrict__ W2, short* __restrict__ Wt2) {
  __shared__ short tl[64 * 72];  // 64 rows x 144B
  const int nb1 = (F / 64) * (H / 64);  // 73 * 71
  int bid = blockIdx.x;
  const float* W; short* Wt; int N, n0, k0;
  if (bid < nb1) {
    W = W1; Wt = Wt1; N = F;
    n0 = (bid % (F / 64)) * 64; k0 = (bid / (F / 64)) * 64;
  } else {
    bid -= nb1;
    W = W2; Wt = Wt2; N = H;
    n0 = (bid % (H / 64)) * 64; k0 = (bid / (H / 64)) * 64;
  }
  const int t = threadIdx.x;
  char* tlb = (char*)tl;
  const int c4 = (t & 15) * 4;   // n-quad base
  const int kq = t >> 4;         // k-quad index 0..15 (k = 4*kq + i)

  // 4 independent loads (16-lane groups read 256B contiguous per row)
  f32x4 v[4];
#pragma unroll
  for (int i = 0; i < 4; ++i)
    v[i] = *(const f32x4*)(W + (size_t)(k0 + 4 * kq + i) * N + n0 + c4);

  // register 4x4 transpose -> 4 b64 writes (needs all of v[0..3] -> loads stay in flight)
#pragma unroll
  for (int j = 0; j < 4; ++j) {
    int n = c4 + j;
    uint2 wv;
    wv.x = cvt_pk_bf16(v[0][j], v[1][j]);   // k = 4kq, 4kq+1
    wv.y = cvt_pk_bf16(v[2][j], v[3][j]);   // k = 4kq+2, 4kq+3
    int sp = ((kq >> 1) + (n >> 2)) & 7;
    *(uint2*)(tlb + n * 144 + sp * 16 + (kq & 1) * 8) = wv;
  }
  __syncthreads();
  // write phase: b128 LDS reads (rotation matched) + 16B/lane coalesced stores
#pragma unroll
  for (int pass = 0; pass < 2; ++pass) {
    int u = pass * 256 + t;
    int n = u >> 3, m = u & 7;
    int sp = (m + (n >> 2)) & 7;
    bf16x8 vv = *(const bf16x8*)(tlb + n * 144 + sp * 16);
    *(bf16x8*)(Wt + (size_t)(n0 + n) * H + k0 + 8 * m) = vv;
  }
}

// ---------------- RoPE + pack (tables in-LDS, vectorized x4) ----------------
__global__ __launch_bounds__(256) void rope_pack_kernel(
    const float* __restrict__ qkv,
    short* __restrict__ Qb, short* __restrict__ Kb, short* __restrict__ Vt) {
  __shared__ float cs[32], sn[32];
  int s = blockIdx.x;
  if (threadIdx.x < 32) {
    float invf = powf(10000.0f, -(float)threadIdx.x / 32.0f);
    float a = (float)s * invf;
    cs[threadIdx.x] = cosf(a);
    sn[threadIdx.x] = sinf(a);
  }
  __syncthreads();
  const float* row = qkv + (size_t)s * F;
  for (int q4 = threadIdx.x; q4 < F / 4; q4 += 256) {
    int c = q4 * 4;
    int hh = c >> 6, d = c & 63;
    f32x4 v = *(const f32x4*)(row + c);
    if (hh <= NH) {  // q heads 0..70, k at 71
      f32x4 r = *(const f32x4*)(row + c + ((d < 32) ? 32 : -32));
      float sgn = (d < 32) ? -1.0f : 1.0f;
      int i0 = d & 31;
      s16x4 o;
#pragma unroll
      for (int j = 0; j < 4; ++j)
        o[j] = f2bf(v[j] * cs[i0 + j] + sgn * r[j] * sn[i0 + j]);
      if (hh < NH) *(s16x4*)(Qb + ((size_t)hh * S + s) * 64 + d) = o;
      else         *(s16x4*)(Kb + (size_t)s * 64 + d) = o;
    } else {  // v: store transposed
#pragma unroll
      for (int j = 0; j < 4; ++j)
        Vt[(size_t)(d + j) * S + s] = f2bf(v[j]);
    }
  }
}

// ---------------- GEMM: C[M][N] = A[M][K] * Bt[N][K]^T, 2-phase pipeline ----------------
// R5 configuration (best measured: ~73-77 us/dispatch, MfmaUtil 22-23%, conflicts 0).
// BM=128, BN=64, BK=64; double-buffered LDS (48KB); XOR-swizzled chunks. FROZEN.
__global__ __launch_bounds__(256, 3) void gemm_bt_kernel(
    const short* __restrict__ A, const short* __restrict__ Bt, float* __restrict__ C,
    int M, int N, int K) {
  __shared__ short As[2 * 128 * 64];
  __shared__ short Bs[2 * 64 * 64];
  const int tid = threadIdx.x;
  const int lane = tid & 63;
  const int wave = tid >> 6;
  const int wr = wave >> 1, wc = wave & 1;
  const int lr = lane & 15, g = lane >> 4;

  const int nwg = gridDim.x;
  int bid = blockIdx.x;
  int wgid = ((nwg & 7) == 0) ? ((bid & 7) * (nwg >> 3) + (bid >> 3)) : bid;
  const int ntm = M >> 7;
  const int tn = wgid / ntm;
  const int tm = wgid % ntm;

  f32x4 acc[4][2] = {};

  int srowA[4], skofA[4];
#pragma unroll
  for (int iss = 0; iss < 4; ++iss) {
    int d = iss * 256 + wave * 64 + lane;
    int row = (d >> 2) & 127;
    int c = (d & 3) ^ ((row >> 1) & 3);
    srowA[iss] = row;
    skofA[iss] = ((d >> 9) << 5) + c * 8;
  }
  int srowB[2], skofB[2];
#pragma unroll
  for (int iss = 0; iss < 2; ++iss) {
    int d = iss * 256 + wave * 64 + lane;
    int row = (d >> 2) & 63;
    int c = (d & 3) ^ ((row >> 1) & 3);
    srowB[iss] = row;
    skofB[iss] = ((d >> 8) << 5) + c * 8;
  }
  int offA[2][4], offB[2][2];
#pragma unroll
  for (int im = 0; im < 4; ++im) {
    int row_a = wr * 64 + im * 16 + lr;
    int sl = (g ^ ((row_a >> 1) & 3)) << 4;
#pragma unroll
    for (int kk = 0; kk < 2; ++kk) offA[kk][im] = kk * 8192 + row_a * 64 + sl;
  }
#pragma unroll
  for (int in = 0; in < 2; ++in) {
    int row_b = wc * 32 + in * 16 + lr;
    int sl = (g ^ ((row_b >> 1) & 3)) << 4;
#pragma unroll
    for (int kk = 0; kk < 2; ++kk) offB[kk][in] = kk * 4096 + row_b * 64 + sl;
  }

  char* AsB = (char*)As;
  char* BsB = (char*)Bs;
  const size_t Abase = (size_t)tm * 128 * K;
  const size_t Bbase = (size_t)tn * 64 * K;

#define STAGE(buf, k0)                                                                  \
  {                                                                                     \
    _Pragma("unroll")                                                                   \
    for (int iss = 0; iss < 4; ++iss)                                                   \
      gload_lds16(A + Abase + (size_t)srowA[iss] * K + (k0) + skofA[iss],               \
                  AsB + (buf) * 16384 + (iss * 4 + wave) * 1024);                       \
    _Pragma("unroll")                                                                   \
    for (int iss = 0; iss < 2; ++iss)                                                   \
      gload_lds16(Bt + Bbase + (size_t)srowB[iss] * K + (k0) + skofB[iss],              \
                  BsB + (buf) * 8192 + (iss * 4 + wave) * 1024);                        \
  }

  STAGE(0, 0);
  __syncthreads();
  const int KS = K >> 6;
  for (int t = 0; t < KS; ++t) {
    const int cur = t & 1;
    if (t + 1 < KS) STAGE(cur ^ 1, (t + 1) << 6);
    const char* Ac = AsB + cur * 16384;
    const char* Bc = BsB + cur * 8192;
    bf16x8 af[2][4], bfr[2][2];
#pragma unroll
    for (int kk = 0; kk < 2; ++kk) {
#pragma unroll
      for (int im = 0; im < 4; ++im) af[kk][im] = *(const bf16x8*)(Ac + offA[kk][im]);
#pragma unroll
      for (int in = 0; in < 2; ++in) bfr[kk][in] = *(const bf16x8*)(Bc + offB[kk][in]);
    }
#pragma unroll
    for (int kk = 0; kk < 2; ++kk)
#pragma unroll
      for (int im = 0; im < 4; ++im)
#pragma unroll
        for (int in = 0; in < 2; ++in)
          acc[im][in] = __builtin_amdgcn_mfma_f32_16x16x32_bf16(af[kk][im], bfr[kk][in], acc[im][in], 0, 0, 0);
    __syncthreads();
  }
#undef STAGE

#pragma unroll
  for (int im = 0; im < 4; ++im) {
#pragma unroll
    for (int in = 0; in < 2; ++in) {
      int row = tm * 128 + wr * 64 + im * 16 + g * 4;
      int col = tn * 64 + wc * 32 + in * 16 + lr;
#pragma unroll
      for (int i = 0; i < 4; ++i)
        C[(size_t)(row + i) * N + col] = acc[im][in][i];
    }
  }
}

// ---------------- fused causal MQA attention (paired-strip, LDS-staged KV) ----------------
DI void attn_step(const char* Kc, const char* Vc, char* P,
                  int key0, int qrow, bf16x8 aQ0, bf16x8 aQ1,
                  f32x4* accO, float& m, float& l, int lr, int g) {
  f32x4 p[4];
#pragma unroll
  for (int nf = 0; nf < 4; ++nf) {
    int row = nf * 16 + lr;
    bf16x8 k0 = ldswz(Kc, row, g);
    bf16x8 k1 = ldswz(Kc, row, g + 4);
    f32x4 z = {};
    z = __builtin_amdgcn_mfma_f32_16x16x32_bf16(k0, aQ0, z, 0, 0, 0);
    p[nf] = __builtin_amdgcn_mfma_f32_16x16x32_bf16(k1, aQ1, z, 0, 0, 0);
  }
  float pmx = -3e30f;
#pragma unroll
  for (int nf = 0; nf < 4; ++nf)
#pragma unroll
    for (int i = 0; i < 4; ++i) {
      int key = key0 + nf * 16 + 4 * g + i;
      float sv = p[nf][i] * K2 + (key <= qrow ? 0.0f : -1e30f);
      p[nf][i] = sv;
      pmx = fmaxf(pmx, sv);
    }
  float pm = redmax_g(pmx);
  float mn = fmaxf(m, pm);
  float scl = __builtin_exp2f(m - mn);
  m = mn;
  float rsx = 0.f;
#pragma unroll
  for (int nf = 0; nf < 4; ++nf) {
    f32x4 pe;
#pragma unroll
    for (int i = 0; i < 4; ++i) {
      pe[i] = __builtin_exp2f(p[nf][i] - m);
      rsx += pe[i];
    }
    uint2 wv;
    wv.x = cvt_pk_bf16(pe[0], pe[1]);
    wv.y = cvt_pk_bf16(pe[2], pe[3]);
    *(uint2*)(P + lr * 144 + nf * 32 + g * 8) = wv;  // P[q=lr][key], stride 144B
  }
  float rs = redsum_g(rsx);
  l = l * scl + rs;
#pragma unroll
  for (int df = 0; df < 4; ++df)
#pragma unroll
    for (int i = 0; i < 4; ++i)
      accO[df][i] *= scl;
#pragma unroll
  for (int st = 0; st < 2; ++st) {
    bf16x8 bP = *(const bf16x8*)(P + lr * 144 + st * 64 + g * 16);
#pragma unroll
    for (int df = 0; df < 4; ++df) {
      bf16x8 aV = ldswz(Vc, df * 16 + lr, g + 4 * st);
      accO[df] = __builtin_amdgcn_mfma_f32_16x16x32_bf16(aV, bP, accO[df], 0, 0, 0);
    }
  }
}

// Grid (8, 71): WG j handles q-tiles A=j and B=15-j (64 rows each; wave w: rows +16w).
__global__ __launch_bounds__(256) void attn_kernel(
    const short* __restrict__ Qb,   // [NH][S][64]
    const short* __restrict__ Kb,   // [S][64]
    const short* __restrict__ Vt,   // [64][S]
    short* __restrict__ merged) {   // [S][H] bf16
  __shared__ short Ks[2][4096];
  __shared__ short Vs[2][4096];
  __shared__ short Ps[4][16 * 72];
  const int lane = threadIdx.x & 63, w = threadIdx.x >> 6;
  const int lr = lane & 15, g = lane >> 4;
  const int j = blockIdx.x, head = blockIdx.y;
  const int kbmax = 15 - j;
  const int qA = j * 64 + w * 16 + lr;
  const int qB = (15 - j) * 64 + w * 16 + lr;
  char* KsB = (char*)Ks;
  char* VsB = (char*)Vs;
  char* P = (char*)Ps[w];

  int crow[2], cslot[2];
#pragma unroll
  for (int i = 0; i < 2; ++i) {
    int c = (i * 4 + w) * 64 + lane;
    crow[i] = c >> 3;
    cslot[i] = (c & 7) ^ (crow[i] & 7);
  }

  const short* qap = Qb + ((size_t)head * S + qA) * 64 + g * 8;
  bf16x8 aQA0 = *(const bf16x8*)(qap);
  bf16x8 aQA1 = *(const bf16x8*)(qap + 32);
  const short* qbp = Qb + ((size_t)head * S + qB) * 64 + g * 8;
  bf16x8 aQB0 = *(const bf16x8*)(qbp);
  bf16x8 aQB1 = *(const bf16x8*)(qbp + 32);

  f32x4 accA[4] = {}, accB[4] = {};
  float mA = -3e30f, lA = 0.f, mB = -3e30f, lB = 0.f;

#define STAGEKV(buf, key0)                                                       \
  {                                                                              \
    _Pragma("unroll")                                                            \
    for (int i = 0; i < 2; ++i) {                                                \
      gload_lds16(Kb + (size_t)((key0) + crow[i]) * 64 + cslot[i] * 8,           \
                  KsB + (buf) * 8192 + (i * 4 + w) * 1024);                      \
      gload_lds16(Vt + (size_t)crow[i] * S + (key0) + cslot[i] * 8,              \
                  VsB + (buf) * 8192 + (i * 4 + w) * 1024);                      \
    }                                                                            \
  }

  STAGEKV(0, 0);
  for (int kb = 0; kb <= kbmax; ++kb) {
    const int cur = kb & 1;
    __syncthreads();  // drains staging vmcnt; all waves done with buf[cur^1]
    if (kb < kbmax) STAGEKV(cur ^ 1, (kb + 1) * 64);
    const char* Kc = KsB + cur * 8192;
    const char* Vc = VsB + cur * 8192;
    attn_step(Kc, Vc, P, kb * 64, qB, aQB0, aQB1, accB, mB, lB, lr, g);
    if (kb <= j)
      attn_step(Kc, Vc, P, kb * 64, qA, aQA0, aQA1, accA, mA, lA, lr, g);
  }
#undef STAGEKV

  float rlA = 1.0f / lA, rlB = 1.0f / lB;
#pragma unroll
  for (int df = 0; df < 4; ++df)
#pragma unroll
    for (int i = 0; i < 4; ++i) {
      int d = head * 64 + df * 16 + 4 * g + i;
      merged[(size_t)qB * H + d] = f2bf(accB[df][i] * rlB);
      merged[(size_t)qA * H + d] = f2bf(accA[df][i] * rlA);
    }
}

extern "C" void kernel_launch(void* const* d_in, const int* in_sizes, int n_in,
                              void* d_out, int out_size, void* d_ws, size_t ws_size,
                              hipStream_t stream) {
  const float* x    = (const float*)d_in[0];
  const float* wqkv = (const float*)d_in[1];
  const float* wd   = (const float*)d_in[2];
  // d_in[3] attention_mask: pure causal, applied analytically
  float* out = (float*)d_out;

  char* ws = (char*)d_ws;
  size_t off = 0;
  short* Wqkvt  = (short*)(ws + off); off += (size_t)F * H * 2;       // [F][H]
  short* Wdt    = (short*)(ws + off); off += (size_t)H * H * 2;       // [H][H]
  short* Qb     = (short*)(ws + off); off += (size_t)NH * S * HD * 2; // [NH][S][64]
  short* Kb     = (short*)(ws + off); off += (size_t)S * HD * 2;
  short* Vtb    = (short*)(ws + off); off += (size_t)HD * S * 2;
  short* merged = (short*)(ws + off); off += (size_t)S * H * 2;       // [S][H]
  short* xb     = (short*)(ws + off); off += (size_t)S * H * 2;       // [S][H]
  float* qkv    = (float*)(ws + off); off += (size_t)S * F * 4;       // [S][F]
  (void)ws_size; (void)in_sizes; (void)n_in; (void)out_size;

  hipLaunchKernelGGL(cast_x_kernel, dim3((S * H / 4 + 255) / 256), dim3(256), 0, stream,
                     x, xb, S * H / 4);
  hipLaunchKernelGGL(transpose2_kernel,
                     dim3((F / 64) * (H / 64) + (H / 64) * (H / 64)), dim3(256), 0, stream,
                     wqkv, Wqkvt, wd, Wdt);
  // QKV GEMM: 73 x 8 = 584 blocks
  hipLaunchKernelGGL(gemm_bt_kernel, dim3((F / 64) * (S / 128)), dim3(256), 0, stream,
                     xb, Wqkvt, qkv, S, F, H);
  hipLaunchKernelGGL(rope_pack_kernel, dim3(S), dim3(256), 0, stream,
                     qkv, Qb, Kb, Vtb);
  hipLaunchKernelGGL(attn_kernel, dim3(8, NH), dim3(256), 0, stream,
                     Qb, Kb, Vtb, merged);
  // dense GEMM: 71 x 8 = 568 blocks
  hipLaunchKernelGGL(gemm_bt_kernel, dim3((H / 64) * (S / 128)), dim3(256), 0, stream,
                     merged, Wdt, out, S, H, H);
}

// Round 17
// 224.600 us; speedup vs baseline: 1.0196x; 1.0196x over previous
//
#include <hip/hip_runtime.h>
#include <hip/hip_bf16.h>

#define DI __device__ __forceinline__

typedef __attribute__((ext_vector_type(8))) short bf16x8;
typedef __attribute__((ext_vector_type(4))) float f32x4;
typedef __attribute__((ext_vector_type(4))) short s16x4;

constexpr int S  = 1024;
constexpr int NH = 71;
constexpr int HD = 64;
constexpr int H  = NH * HD;        // 4544
constexpr int F  = (NH + 2) * HD;  // 4672
constexpr float K2 = 0.125f * 1.44269504f;  // SCALE * log2(e)

DI short f2bf(float f) {
  union { float f; unsigned u; } v; v.f = f;
  unsigned r = v.u + 0x7fffu + ((v.u >> 16) & 1u);
  return (short)(r >> 16);
}
DI unsigned cvt_pk_bf16(float lo, float hi) {
  unsigned r;
  asm("v_cvt_pk_bf16_f32 %0, %1, %2" : "=v"(r) : "v"(lo), "v"(hi));
  return r;
}
// reduce over lanes {lr, lr+16, lr+32, lr+48}: xor16 via ds_swizzle, xor32 via shfl
DI float redmax_g(float x) {
  float y = fmaxf(x, __int_as_float(__builtin_amdgcn_ds_swizzle(__float_as_int(x), 0x401F)));
  return fmaxf(y, __shfl_xor(y, 32));
}
DI float redsum_g(float x) {
  float y = x + __int_as_float(__builtin_amdgcn_ds_swizzle(__float_as_int(x), 0x401F));
  return y + __shfl_xor(y, 32);
}

DI void gload_lds16(const void* g, void* l) {
  __builtin_amdgcn_global_load_lds(
      (const __attribute__((address_space(1))) unsigned int*)g,
      (__attribute__((address_space(3))) unsigned int*)l, 16, 0, 0);
}

// swizzled LDS tile read: [64 rows][8 slots of 16B], slot XOR row&7
DI bf16x8 ldswz(const char* base, int row, int slot) {
  return *(const bf16x8*)(base + row * 128 + ((slot ^ (row & 7)) << 4));
}

// ---------------- cast x fp32 -> bf16 ----------------
__global__ void cast_x_kernel(const float* __restrict__ x, short* __restrict__ xb, int n4) {
  int i = blockIdx.x * blockDim.x + threadIdx.x;
  if (i >= n4) return;
  f32x4 v = ((const f32x4*)x)[i];
  s16x4 o = { f2bf(v.x), f2bf(v.y), f2bf(v.z), f2bf(v.w) };
  ((s16x4*)xb)[i] = o;
}

// ---------------- merged transpose+cast for BOTH weights (DMA-staged) ----------------
// W[K][N] f32 -> Wt[N][H] bf16 (K = H for both). Job 1: wqkv (N=F), job 2: wd (N=H).
// R14/R15/R16 lesson: compiler serializes any VGPR-routed load chain here (VGPR=16
// three times). Fix: route loads through global_load_lds DMA (no VGPRs involved):
//   1) stage 64x64 f32 tile LINEAR in LDS (16 wave-DMA ops, 256B coalesced rows)
//   2) transpose LDS-side: 8x ds_read_b32 down column n (n=lane -> 2-way, free),
//      cvt_pk x4, ds_write_b128 into bf16 tile (144B rows, rotated 16B slots)
//   3) b128 reads (rotation-matched) + 128B-contiguous global stores
__global__ __launch_bounds__(256) void transpose2_kernel(
    const float* __restrict__ W1, short* __restrict__ Wt1,
    const float* __restrict__ W2, short* __restrict__ Wt2) {
  __shared__ float tf[64 * 64];   // 16 KB, linear [k-row][n-col]
  __shared__ short tb[64 * 72];   // 9 KB, [n-row x 144B]
  const int nb1 = (F / 64) * (H / 64);  // 73 * 71
  int bid = blockIdx.x;
  const float* W; short* Wt; int N, n0, k0;
  if (bid < nb1) {
    W = W1; Wt = Wt1; N = F;
    n0 = (bid % (F / 64)) * 64; k0 = (bid / (F / 64)) * 64;
  } else {
    bid -= nb1;
    W = W2; Wt = Wt2; N = H;
    n0 = (bid % (H / 64)) * 64; k0 = (bid / (H / 64)) * 64;
  }
  const int t = threadIdx.x;
  const int lane = t & 63, wave = t >> 6;
  char* tfb = (char*)tf;
  char* tbb = (char*)tb;

  // phase 1: DMA-stage f32 tile (chunk c = (i*4+wave)*64 + lane; LDS byte = c*16)
#pragma unroll
  for (int i = 0; i < 4; ++i) {
    int row = (i * 4 + wave) * 4 + (lane >> 4);
    gload_lds16(W + (size_t)(k0 + row) * N + n0 + (lane & 15) * 4,
                tfb + (i * 4 + wave) * 1024);
  }
  __syncthreads();  // drains DMA vmcnt

  // phase 2: column transpose. thread (n=lane, m in {wave, wave+4}):
  // 8x ds_read_b32 (bank = n%32, n=lane -> 2-way free), pack, b128 write.
#pragma unroll
  for (int pass = 0; pass < 2; ++pass) {
    int m = wave + 4 * pass;
    int n = lane;
    float v[8];
#pragma unroll
    for (int i = 0; i < 8; ++i)
      v[i] = tf[(8 * m + i) * 64 + n];
    uint4 wv;
    wv.x = cvt_pk_bf16(v[0], v[1]);
    wv.y = cvt_pk_bf16(v[2], v[3]);
    wv.z = cvt_pk_bf16(v[4], v[5]);
    wv.w = cvt_pk_bf16(v[6], v[7]);
    int sp = (m + (n >> 2)) & 7;
    *(uint4*)(tbb + n * 144 + sp * 16) = wv;
  }
  __syncthreads();

  // phase 3: b128 reads + coalesced 128B-per-row global stores
#pragma unroll
  for (int pass = 0; pass < 2; ++pass) {
    int u = pass * 256 + t;
    int n = u >> 3, m = u & 7;
    int sp = (m + (n >> 2)) & 7;
    bf16x8 vv = *(const bf16x8*)(tbb + n * 144 + sp * 16);
    *(bf16x8*)(Wt + (size_t)(n0 + n) * H + k0 + 8 * m) = vv;
  }
}

// ---------------- RoPE + pack (tables in-LDS, vectorized x4) ----------------
__global__ __launch_bounds__(256) void rope_pack_kernel(
    const float* __restrict__ qkv,
    short* __restrict__ Qb, short* __restrict__ Kb, short* __restrict__ Vt) {
  __shared__ float cs[32], sn[32];
  int s = blockIdx.x;
  if (threadIdx.x < 32) {
    float invf = powf(10000.0f, -(float)threadIdx.x / 32.0f);
    float a = (float)s * invf;
    cs[threadIdx.x] = cosf(a);
    sn[threadIdx.x] = sinf(a);
  }
  __syncthreads();
  const float* row = qkv + (size_t)s * F;
  for (int q4 = threadIdx.x; q4 < F / 4; q4 += 256) {
    int c = q4 * 4;
    int hh = c >> 6, d = c & 63;
    f32x4 v = *(const f32x4*)(row + c);
    if (hh <= NH) {  // q heads 0..70, k at 71
      f32x4 r = *(const f32x4*)(row + c + ((d < 32) ? 32 : -32));
      float sgn = (d < 32) ? -1.0f : 1.0f;
      int i0 = d & 31;
      s16x4 o;
#pragma unroll
      for (int j = 0; j < 4; ++j)
        o[j] = f2bf(v[j] * cs[i0 + j] + sgn * r[j] * sn[i0 + j]);
      if (hh < NH) *(s16x4*)(Qb + ((size_t)hh * S + s) * 64 + d) = o;
      else         *(s16x4*)(Kb + (size_t)s * 64 + d) = o;
    } else {  // v: store transposed
#pragma unroll
      for (int j = 0; j < 4; ++j)
        Vt[(size_t)(d + j) * S + s] = f2bf(v[j]);
    }
  }
}

// ---------------- GEMM: C[M][N] = A[M][K] * Bt[N][K]^T, 2-phase pipeline ----------------
// R5 configuration (best measured: ~73-77 us/dispatch, MfmaUtil 22-23%, conflicts 0).
// BM=128, BN=64, BK=64; double-buffered LDS (48KB); XOR-swizzled chunks. FROZEN.
__global__ __launch_bounds__(256, 3) void gemm_bt_kernel(
    const short* __restrict__ A, const short* __restrict__ Bt, float* __restrict__ C,
    int M, int N, int K) {
  __shared__ short As[2 * 128 * 64];
  __shared__ short Bs[2 * 64 * 64];
  const int tid = threadIdx.x;
  const int lane = tid & 63;
  const int wave = tid >> 6;
  const int wr = wave >> 1, wc = wave & 1;
  const int lr = lane & 15, g = lane >> 4;

  const int nwg = gridDim.x;
  int bid = blockIdx.x;
  int wgid = ((nwg & 7) == 0) ? ((bid & 7) * (nwg >> 3) + (bid >> 3)) : bid;
  const int ntm = M >> 7;
  const int tn = wgid / ntm;
  const int tm = wgid % ntm;

  f32x4 acc[4][2] = {};

  int srowA[4], skofA[4];
#pragma unroll
  for (int iss = 0; iss < 4; ++iss) {
    int d = iss * 256 + wave * 64 + lane;
    int row = (d >> 2) & 127;
    int c = (d & 3) ^ ((row >> 1) & 3);
    srowA[iss] = row;
    skofA[iss] = ((d >> 9) << 5) + c * 8;
  }
  int srowB[2], skofB[2];
#pragma unroll
  for (int iss = 0; iss < 2; ++iss) {
    int d = iss * 256 + wave * 64 + lane;
    int row = (d >> 2) & 63;
    int c = (d & 3) ^ ((row >> 1) & 3);
    srowB[iss] = row;
    skofB[iss] = ((d >> 8) << 5) + c * 8;
  }
  int offA[2][4], offB[2][2];
#pragma unroll
  for (int im = 0; im < 4; ++im) {
    int row_a = wr * 64 + im * 16 + lr;
    int sl = (g ^ ((row_a >> 1) & 3)) << 4;
#pragma unroll
    for (int kk = 0; kk < 2; ++kk) offA[kk][im] = kk * 8192 + row_a * 64 + sl;
  }
#pragma unroll
  for (int in = 0; in < 2; ++in) {
    int row_b = wc * 32 + in * 16 + lr;
    int sl = (g ^ ((row_b >> 1) & 3)) << 4;
#pragma unroll
    for (int kk = 0; kk < 2; ++kk) offB[kk][in] = kk * 4096 + row_b * 64 + sl;
  }

  char* AsB = (char*)As;
  char* BsB = (char*)Bs;
  const size_t Abase = (size_t)tm * 128 * K;
  const size_t Bbase = (size_t)tn * 64 * K;

#define STAGE(buf, k0)                                                                  \
  {                                                                                     \
    _Pragma("unroll")                                                                   \
    for (int iss = 0; iss < 4; ++iss)                                                   \
      gload_lds16(A + Abase + (size_t)srowA[iss] * K + (k0) + skofA[iss],               \
                  AsB + (buf) * 16384 + (iss * 4 + wave) * 1024);                       \
    _Pragma("unroll")                                                                   \
    for (int iss = 0; iss < 2; ++iss)                                                   \
      gload_lds16(Bt + Bbase + (size_t)srowB[iss] * K + (k0) + skofB[iss],              \
                  BsB + (buf) * 8192 + (iss * 4 + wave) * 1024);                        \
  }

  STAGE(0, 0);
  __syncthreads();
  const int KS = K >> 6;
  for (int t = 0; t < KS; ++t) {
    const int cur = t & 1;
    if (t + 1 < KS) STAGE(cur ^ 1, (t + 1) << 6);
    const char* Ac = AsB + cur * 16384;
    const char* Bc = BsB + cur * 8192;
    bf16x8 af[2][4], bfr[2][2];
#pragma unroll
    for (int kk = 0; kk < 2; ++kk) {
#pragma unroll
      for (int im = 0; im < 4; ++im) af[kk][im] = *(const bf16x8*)(Ac + offA[kk][im]);
#pragma unroll
      for (int in = 0; in < 2; ++in) bfr[kk][in] = *(const bf16x8*)(Bc + offB[kk][in]);
    }
#pragma unroll
    for (int kk = 0; kk < 2; ++kk)
#pragma unroll
      for (int im = 0; im < 4; ++im)
#pragma unroll
        for (int in = 0; in < 2; ++in)
          acc[im][in] = __builtin_amdgcn_mfma_f32_16x16x32_bf16(af[kk][im], bfr[kk][in], acc[im][in], 0, 0, 0);
    __syncthreads();
  }
#undef STAGE

#pragma unroll
  for (int im = 0; im < 4; ++im) {
#pragma unroll
    for (int in = 0; in < 2; ++in) {
      int row = tm * 128 + wr * 64 + im * 16 + g * 4;
      int col = tn * 64 + wc * 32 + in * 16 + lr;
#pragma unroll
      for (int i = 0; i < 4; ++i)
        C[(size_t)(row + i) * N + col] = acc[im][in][i];
    }
  }
}

// ---------------- fused causal MQA attention (paired-strip, LDS-staged KV) ----------------
DI void attn_step(const char* Kc, const char* Vc, char* P,
                  int key0, int qrow, bf16x8 aQ0, bf16x8 aQ1,
                  f32x4* accO, float& m, float& l, int lr, int g) {
  f32x4 p[4];
#pragma unroll
  for (int nf = 0; nf < 4; ++nf) {
    int row = nf * 16 + lr;
    bf16x8 k0 = ldswz(Kc, row, g);
    bf16x8 k1 = ldswz(Kc, row, g + 4);
    f32x4 z = {};
    z = __builtin_amdgcn_mfma_f32_16x16x32_bf16(k0, aQ0, z, 0, 0, 0);
    p[nf] = __builtin_amdgcn_mfma_f32_16x16x32_bf16(k1, aQ1, z, 0, 0, 0);
  }
  float pmx = -3e30f;
#pragma unroll
  for (int nf = 0; nf < 4; ++nf)
#pragma unroll
    for (int i = 0; i < 4; ++i) {
      int key = key0 + nf * 16 + 4 * g + i;
      float sv = p[nf][i] * K2 + (key <= qrow ? 0.0f : -1e30f);
      p[nf][i] = sv;
      pmx = fmaxf(pmx, sv);
    }
  float pm = redmax_g(pmx);
  float mn = fmaxf(m, pm);
  float scl = __builtin_exp2f(m - mn);
  m = mn;
  float rsx = 0.f;
#pragma unroll
  for (int nf = 0; nf < 4; ++nf) {
    f32x4 pe;
#pragma unroll
    for (int i = 0; i < 4; ++i) {
      pe[i] = __builtin_exp2f(p[nf][i] - m);
      rsx += pe[i];
    }
    uint2 wv;
    wv.x = cvt_pk_bf16(pe[0], pe[1]);
    wv.y = cvt_pk_bf16(pe[2], pe[3]);
    *(uint2*)(P + lr * 144 + nf * 32 + g * 8) = wv;  // P[q=lr][key], stride 144B
  }
  float rs = redsum_g(rsx);
  l = l * scl + rs;
#pragma unroll
  for (int df = 0; df < 4; ++df)
#pragma unroll
    for (int i = 0; i < 4; ++i)
      accO[df][i] *= scl;
#pragma unroll
  for (int st = 0; st < 2; ++st) {
    bf16x8 bP = *(const bf16x8*)(P + lr * 144 + st * 64 + g * 16);
#pragma unroll
    for (int df = 0; df < 4; ++df) {
      bf16x8 aV = ldswz(Vc, df * 16 + lr, g + 4 * st);
      accO[df] = __builtin_amdgcn_mfma_f32_16x16x32_bf16(aV, bP, accO[df], 0, 0, 0);
    }
  }
}

// Grid (8, 71): WG j handles q-tiles A=j and B=15-j (64 rows each; wave w: rows +16w).
__global__ __launch_bounds__(256) void attn_kernel(
    const short* __restrict__ Qb,   // [NH][S][64]
    const short* __restrict__ Kb,   // [S][64]
    const short* __restrict__ Vt,   // [64][S]
    short* __restrict__ merged) {   // [S][H] bf16
  __shared__ short Ks[2][4096];
  __shared__ short Vs[2][4096];
  __shared__ short Ps[4][16 * 72];
  const int lane = threadIdx.x & 63, w = threadIdx.x >> 6;
  const int lr = lane & 15, g = lane >> 4;
  const int j = blockIdx.x, head = blockIdx.y;
  const int kbmax = 15 - j;
  const int qA = j * 64 + w * 16 + lr;
  const int qB = (15 - j) * 64 + w * 16 + lr;
  char* KsB = (char*)Ks;
  char* VsB = (char*)Vs;
  char* P = (char*)Ps[w];

  int crow[2], cslot[2];
#pragma unroll
  for (int i = 0; i < 2; ++i) {
    int c = (i * 4 + w) * 64 + lane;
    crow[i] = c >> 3;
    cslot[i] = (c & 7) ^ (crow[i] & 7);
  }

  const short* qap = Qb + ((size_t)head * S + qA) * 64 + g * 8;
  bf16x8 aQA0 = *(const bf16x8*)(qap);
  bf16x8 aQA1 = *(const bf16x8*)(qap + 32);
  const short* qbp = Qb + ((size_t)head * S + qB) * 64 + g * 8;
  bf16x8 aQB0 = *(const bf16x8*)(qbp);
  bf16x8 aQB1 = *(const bf16x8*)(qbp + 32);

  f32x4 accA[4] = {}, accB[4] = {};
  float mA = -3e30f, lA = 0.f, mB = -3e30f, lB = 0.f;

#define STAGEKV(buf, key0)                                                       \
  {                                                                              \
    _Pragma("unroll")                                                            \
    for (int i = 0; i < 2; ++i) {                                                \
      gload_lds16(Kb + (size_t)((key0) + crow[i]) * 64 + cslot[i] * 8,           \
                  KsB + (buf) * 8192 + (i * 4 + w) * 1024);                      \
      gload_lds16(Vt + (size_t)crow[i] * S + (key0) + cslot[i] * 8,              \
                  VsB + (buf) * 8192 + (i * 4 + w) * 1024);                      \
    }                                                                            \
  }

  STAGEKV(0, 0);
  for (int kb = 0; kb <= kbmax; ++kb) {
    const int cur = kb & 1;
    __syncthreads();  // drains staging vmcnt; all waves done with buf[cur^1]
    if (kb < kbmax) STAGEKV(cur ^ 1, (kb + 1) * 64);
    const char* Kc = KsB + cur * 8192;
    const char* Vc = VsB + cur * 8192;
    attn_step(Kc, Vc, P, kb * 64, qB, aQB0, aQB1, accB, mB, lB, lr, g);
    if (kb <= j)
      attn_step(Kc, Vc, P, kb * 64, qA, aQA0, aQA1, accA, mA, lA, lr, g);
  }
#undef STAGEKV

  float rlA = 1.0f / lA, rlB = 1.0f / lB;
#pragma unroll
  for (int df = 0; df < 4; ++df)
#pragma unroll
    for (int i = 0; i < 4; ++i) {
      int d = head * 64 + df * 16 + 4 * g + i;
      merged[(size_t)qB * H + d] = f2bf(accB[df][i] * rlB);
      merged[(size_t)qA * H + d] = f2bf(accA[df][i] * rlA);
    }
}

extern "C" void kernel_launch(void* const* d_in, const int* in_sizes, int n_in,
                              void* d_out, int out_size, void* d_ws, size_t ws_size,
                              hipStream_t stream) {
  const float* x    = (const float*)d_in[0];
  const float* wqkv = (const float*)d_in[1];
  const float* wd   = (const float*)d_in[2];
  // d_in[3] attention_mask: pure causal, applied analytically
  float* out = (float*)d_out;

  char* ws = (char*)d_ws;
  size_t off = 0;
  short* Wqkvt  = (short*)(ws + off); off += (size_t)F * H * 2;       // [F][H]
  short* Wdt    = (short*)(ws + off); off += (size_t)H * H * 2;       // [H][H]
  short* Qb     = (short*)(ws + off); off += (size_t)NH * S * HD * 2; // [NH][S][64]
  short* Kb     = (short*)(ws + off); off += (size_t)S * HD * 2;
  short* Vtb    = (short*)(ws + off); off += (size_t)HD * S * 2;
  short* merged = (short*)(ws + off); off += (size_t)S * H * 2;       // [S][H]
  short* xb     = (short*)(ws + off); off += (size_t)S * H * 2;       // [S][H]
  float* qkv    = (float*)(ws + off); off += (size_t)S * F * 4;       // [S][F]
  (void)ws_size; (void)in_sizes; (void)n_in; (void)out_size;

  hipLaunchKernelGGL(cast_x_kernel, dim3((S * H / 4 + 255) / 256), dim3(256), 0, stream,
                     x, xb, S * H / 4);
  hipLaunchKernelGGL(transpose2_kernel,
                     dim3((F / 64) * (H / 64) + (H / 64) * (H / 64)), dim3(256), 0, stream,
                     wqkv, Wqkvt, wd, Wdt);
  // QKV GEMM: 73 x 8 = 584 blocks
  hipLaunchKernelGGL(gemm_bt_kernel, dim3((F / 64) * (S / 128)), dim3(256), 0, stream,
                     xb, Wqkvt, qkv, S, F, H);
  hipLaunchKernelGGL(rope_pack_kernel, dim3(S), dim3(256), 0, stream,
                     qkv, Qb, Kb, Vtb);
  hipLaunchKernelGGL(attn_kernel, dim3(8, NH), dim3(256), 0, stream,
                     Qb, Kb, Vtb, merged);
  // dense GEMM: 71 x 8 = 568 blocks
  hipLaunchKernelGGL(gemm_bt_kernel, dim3((H / 64) * (S / 128)), dim3(256), 0, stream,
                     merged, Wdt, out, S, H, H);
}